// Round 5
// baseline (11657.397 us; speedup 1.0000x reference)
//
#include <hip/hip_runtime.h>

// Problem sizes (fixed by the reference)
constexpr int D_ = 1024, E_ = 2048, B_ = 16, T_ = 1024;
constexpr int NWG = 128, TPB = 512;   // 128 WGs: 16 W1-rows, 8 W2/Wc/Wgx-rows each

typedef short bf16x8 __attribute__((ext_vector_type(8)));
typedef float f32x4  __attribute__((ext_vector_type(4)));

// ---- LDS byte offsets ----
constexpr int W1F   = 0;        // W1 frags:   64 kc * 1024 B = 64 KB
constexpr int W2CF  = 65536;    // [W2;Wc] frags: 64 kc * 1024 B = 64 KB
constexpr int WGXF  = 131072;   // Wgx compact frags: 32 kc * 512 B = 16 KB
constexpr int ZB    = 147456;   // 16 B zero block (gate cols 8..15)
constexpr int REDo  = 147472;   // 8 waves * 272 f32 = 8704 B (stride-17 rows)
constexpr int GREDo = 156176;   // 8 waves * 144 f32 = 4608 B (stride-9 rows)
constexpr int GPo   = 160784;   // 128 f32 gate-x partial (persists P1->P2)
constexpr int BIo   = 161296;   // 8 f32 bias slice
constexpr int LDS_BYTES = 161328;
static_assert(LDS_BYTES <= 163840, "LDS over 160KB");
constexpr int REDS = 272;       // REDF stride per wave (floats)
constexpr int GRS  = 144;       // GREDF stride per wave (floats)

// ---- device-coherent (write-through) store helpers ----
__device__ __forceinline__ void stcg_u(unsigned* p, unsigned v) {
    __hip_atomic_store(p, v, __ATOMIC_RELAXED, __HIP_MEMORY_SCOPE_AGENT);
}

// ---- bf16 helpers ----
__device__ __forceinline__ unsigned f2bf(float f) {
    unsigned u; __builtin_memcpy(&u, &f, 4);
    u += 0x7fffu + ((u >> 16) & 1u);   // RNE
    return u >> 16;
}
__device__ __forceinline__ unsigned packbf(float lo, float hi) {
    return f2bf(lo) | (f2bf(hi) << 16);
}
__device__ __forceinline__ bf16x8 pack8(float4 a, float4 b) {
    union { unsigned short us[8]; bf16x8 v; } r;
    r.us[0] = (unsigned short)f2bf(a.x); r.us[1] = (unsigned short)f2bf(a.y);
    r.us[2] = (unsigned short)f2bf(a.z); r.us[3] = (unsigned short)f2bf(a.w);
    r.us[4] = (unsigned short)f2bf(b.x); r.us[5] = (unsigned short)f2bf(b.y);
    r.us[6] = (unsigned short)f2bf(b.z); r.us[7] = (unsigned short)f2bf(b.w);
    return r.v;
}
__device__ __forceinline__ bf16x8 frag_u4(uint4 u) {
    union { uint4 u4; bf16x8 v; } r; r.u4 = u; return r.v;
}

// ---- flag-based grid barrier (plain single-writer flags, no atomics) ----
// Producer g posts flag[g]=val after its exchange stores are drained
// (vmcnt(0) => visible at the coherence point before the flag store issues).
// Consumer: wave 0 polls all 128 flags (2 per lane, 8B acquire loads);
// "all flags >= tgt" has the same monotonic-invariant safety as a counter.
// The ACQUIRE on the detecting load emits buffer_inv (clean-line invalidate
// of L1/L2), so subsequent PLAIN cached loads of the exchange buffers are
// guaranteed fresh — first WG per XCD misses to IF$, the rest hit L2.
__device__ __forceinline__ void flag_post(unsigned* flag, unsigned val) {
    asm volatile("s_waitcnt vmcnt(0)" ::: "memory");   // drain data stores
    __syncthreads();                                   // all waves drained
    if (threadIdx.x == 0) stcg_u(flag, val);
}
__device__ __forceinline__ void flag_wait(const unsigned* flags, unsigned tgt) {
    if (threadIdx.x < 64) {
        const unsigned long long* p =
            (const unsigned long long*)flags + threadIdx.x;
        while (true) {
            unsigned long long u = __hip_atomic_load(
                p, __ATOMIC_ACQUIRE, __HIP_MEMORY_SCOPE_AGENT);
            unsigned lo = (unsigned)u, hi = (unsigned)(u >> 32);
            if (__all((lo >= tgt) && (hi >= tgt))) break;
            __builtin_amdgcn_s_sleep(1);
        }
    }
    __syncthreads();
}

__global__ void __launch_bounds__(TPB, 1)
elman5(const float* __restrict__ x, const float* __restrict__ h0,
       const float* __restrict__ W1, const float* __restrict__ W2g,
       const float* __restrict__ Wgx, const float* __restrict__ Wgh,
       const float* __restrict__ bias, float* __restrict__ out,
       unsigned* __restrict__ flagsA, unsigned* __restrict__ flagsB,
       unsigned* __restrict__ hx   /* [B][D/2] bf16x2, b-major carried h */,
       unsigned* __restrict__ hidx /* [B][E/2] bf16x2, b-major hidden */)
{
    extern __shared__ char sm[];
    float* REDF  = (float*)(sm + REDo);
    float* GREDF = (float*)(sm + GREDo);
    float* GPF   = (float*)(sm + GPo);
    float* BIF   = (float*)(sm + BIo);

    const int g = blockIdx.x, tid = threadIdx.x;
    const int l = tid & 63, wv = tid >> 6;   // lane, wave
    const int c16 = l & 15, q = l >> 4;      // frag col / k-octet group

    // ================= prologue: build bf16 fragment LDS =================
    {
        float* wght = (float*)(sm + W2CF);
        for (int i = tid; i < 8 * D_; i += TPB)
            wght[i] = Wgh[(size_t)(g * 8 + (i >> 10)) * D_ + (i & 1023)];
        if (tid < 8) BIF[tid] = bias[g * 8 + tid];
        if (tid == 0) *(float4*)(sm + ZB) = float4{0, 0, 0, 0};
        __syncthreads();

        // Wc = Wgh_slice @ W2  (f32, into W1F region)
        float* wcf = (float*)(sm + W1F);
        {
            const int k4 = tid * 4;
            float4 acc[8];
            #pragma unroll
            for (int r = 0; r < 8; ++r) acc[r] = float4{0, 0, 0, 0};
            const float* wp = W2g + k4;
            for (int m = 0; m < D_; ++m) {
                float4 wvv = *(const float4*)wp; wp += E_;
                #pragma unroll
                for (int r = 0; r < 8; ++r) {
                    float gm = wght[r * D_ + m];
                    acc[r].x = fmaf(gm, wvv.x, acc[r].x);
                    acc[r].y = fmaf(gm, wvv.y, acc[r].y);
                    acc[r].z = fmaf(gm, wvv.z, acc[r].z);
                    acc[r].w = fmaf(gm, wvv.w, acc[r].w);
                }
            }
            __syncthreads();
            #pragma unroll
            for (int r = 0; r < 8; ++r) *(float4*)(wcf + r * E_ + k4) = acc[r];
        }
        __syncthreads();

        // pack [W2;Wc] frags into W2CF
        for (int i = tid; i < 4096; i += TPB) {
            int kc = i >> 6, l2 = i & 63, cc = l2 & 15, qq = l2 >> 4;
            int k = kc * 32 + qq * 8;
            float4 lo, hi;
            if (cc < 8) {
                const float* src = W2g + (size_t)(g * 8 + cc) * E_ + k;
                lo = *(const float4*)src; hi = *(const float4*)(src + 4);
            } else {
                const float* src = wcf + (cc - 8) * E_ + k;
                lo = *(const float4*)src; hi = *(const float4*)(src + 4);
            }
            *(bf16x8*)(sm + W2CF + i * 16) = pack8(lo, hi);
        }
        __syncthreads();

        // pack W1 frags (16 rows, K=2048)
        for (int i = tid; i < 4096; i += TPB) {
            int kc = i >> 6, l2 = i & 63, cc = l2 & 15, qq = l2 >> 4;
            const float* src = W1 + (size_t)(g * 16 + cc) * (2 * D_) + kc * 32 + qq * 8;
            *(bf16x8*)(sm + W1F + i * 16) =
                pack8(*(const float4*)src, *(const float4*)(src + 4));
        }
        // pack Wgx compact frags (8 real cols only)
        for (int i = tid; i < 1024; i += TPB) {
            int kc = i >> 5, qq = (i >> 3) & 3, cc = i & 7;
            const float* src = Wgx + (size_t)(g * 8 + cc) * D_ + kc * 32 + qq * 8;
            *(bf16x8*)(sm + WGXF + kc * 512 + qq * 128 + cc * 16) =
                pack8(*(const float4*)src, *(const float4*)(src + 4));
        }
        __syncthreads();
    }

    const char* gz = sm + ZB;

    // ================= recurrence =================
    f32x4 accP1 = {0.f, 0.f, 0.f, 0.f}, accG = {0.f, 0.f, 0.f, 0.f};

    // x-work for t=0
    {
        #pragma unroll
        for (int i = 0; i < 4; ++i) {
            int kc = wv + i * 8;
            const float* xp = x + c16 * D_ + kc * 32 + q * 8;
            bf16x8 af = pack8(*(const float4*)xp, *(const float4*)(xp + 4));
            bf16x8 w1 = *(const bf16x8*)(sm + W1F + kc * 1024 + l * 16);
            accP1 = __builtin_amdgcn_mfma_f32_16x16x32_bf16(af, w1, accP1, 0, 0, 0);
            const char* ga = (c16 < 8) ? (sm + WGXF + kc * 512 + q * 128 + c16 * 16) : gz;
            bf16x8 wg = *(const bf16x8*)ga;
            accG = __builtin_amdgcn_mfma_f32_16x16x32_bf16(af, wg, accG, 0, 0, 0);
        }
    }

    for (int t = 0; t < T_; ++t) {
        if (t) flag_wait(flagsB, (unsigned)t);   // h(t-1) visible everywhere

        // ---- P1 h-part
        if (t == 0) {
            #pragma unroll
            for (int i = 0; i < 4; ++i) {
                int kc = 32 + wv + i * 8;
                const float* hp = h0 + c16 * D_ + (kc - 32) * 32 + q * 8;
                bf16x8 af = pack8(*(const float4*)hp, *(const float4*)(hp + 4));
                bf16x8 w1 = *(const bf16x8*)(sm + W1F + kc * 1024 + l * 16);
                accP1 = __builtin_amdgcn_mfma_f32_16x16x32_bf16(af, w1, accP1, 0, 0, 0);
            }
        } else {
            #pragma unroll
            for (int i = 0; i < 4; ++i) {
                int kc = 32 + wv + i * 8;
                // plain cached 16B load — fresh thanks to acquire buffer_inv
                uint4 u = *(const uint4*)(hx + c16 * (D_ / 2) + (kc - 32) * 16 + q * 4);
                bf16x8 w1 = *(const bf16x8*)(sm + W1F + kc * 1024 + l * 16);
                accP1 = __builtin_amdgcn_mfma_f32_16x16x32_bf16(frag_u4(u), w1, accP1, 0, 0, 0);
            }
        }

        // ---- reduce P1 + gate partials across waves
        #pragma unroll
        for (int i = 0; i < 4; ++i)
            REDF[wv * REDS + (q * 4 + i) * 17 + c16] = accP1[i];
        if (c16 < 8) {
            #pragma unroll
            for (int i = 0; i < 4; ++i)
                GREDF[wv * GRS + (q * 4 + i) * 9 + c16] = accG[i];
        }
        __syncthreads();
        if (tid < 256) {                 // hidden = tanh(sum); fused bf16 publish
            int b = tid >> 4, wr = tid & 15;
            float s = 0;
            #pragma unroll
            for (int w = 0; w < 8; ++w) s += REDF[w * REDS + b * 17 + wr];
            float tv = tanhf(s);
            float nb = __shfl_down(tv, 1, 64);   // neighbor wr+1 (same wave)
            if (!(wr & 1))
                stcg_u(hidx + b * (E_ / 2) + g * 8 + (wr >> 1), packbf(tv, nb));
        } else if (tid < 384) {          // gate-x partial -> LDS (read in P2)
            int gt = tid - 256, b = gt >> 3, rp = gt & 7;
            float s = 0;
            #pragma unroll
            for (int w = 0; w < 8; ++w) s += GREDF[w * GRS + b * 9 + rp];
            GPF[gt] = s;
        }
        flag_post(flagsA + g, (unsigned)(t + 1));   // hidden published

        // ---- x-work for t+1 (overlaps waitA of other WGs)
        f32x4 accP1n = {0.f, 0.f, 0.f, 0.f}, accGn = {0.f, 0.f, 0.f, 0.f};
        if (t + 1 < T_) {
            const float* xt = x + (size_t)(t + 1) * (B_ * D_);
            #pragma unroll
            for (int i = 0; i < 4; ++i) {
                int kc = wv + i * 8;
                const float* xp = xt + c16 * D_ + kc * 32 + q * 8;
                bf16x8 af = pack8(*(const float4*)xp, *(const float4*)(xp + 4));
                bf16x8 w1 = *(const bf16x8*)(sm + W1F + kc * 1024 + l * 16);
                accP1n = __builtin_amdgcn_mfma_f32_16x16x32_bf16(af, w1, accP1n, 0, 0, 0);
                const char* ga = (c16 < 8) ? (sm + WGXF + kc * 512 + q * 128 + c16 * 16) : gz;
                bf16x8 wg = *(const bf16x8*)ga;
                accGn = __builtin_amdgcn_mfma_f32_16x16x32_bf16(af, wg, accGn, 0, 0, 0);
            }
        }

        flag_wait(flagsA, (unsigned)(t + 1));   // all hidden slices ready

        // ---- P2: [hnew; u_c] = hidden @ [W2;Wc]^T
        f32x4 acc2 = {0.f, 0.f, 0.f, 0.f};
        #pragma unroll
        for (int i = 0; i < 8; ++i) {
            int kc = wv + i * 8;
            uint4 u = *(const uint4*)(hidx + c16 * (E_ / 2) + kc * 16 + q * 4);
            bf16x8 w2 = *(const bf16x8*)(sm + W2CF + kc * 1024 + l * 16);
            acc2 = __builtin_amdgcn_mfma_f32_16x16x32_bf16(frag_u4(u), w2, acc2, 0, 0, 0);
        }
        #pragma unroll
        for (int i = 0; i < 4; ++i)
            REDF[wv * REDS + (q * 4 + i) * 17 + c16] = acc2[i];
        __syncthreads();
        if (tid < 128) {                 // finalize out = hnew * silu(u); publish h
            int b = tid >> 3, r = tid & 7;
            float hn = 0, uv = 0;
            #pragma unroll
            for (int w = 0; w < 8; ++w) {
                hn += REDF[w * REDS + b * 17 + r];
                uv += REDF[w * REDS + b * 17 + 8 + r];
            }
            uv += GPF[b * 8 + r] + BIF[r];
            float sig = 1.0f / (1.0f + __expf(-uv));
            float o = hn * (uv * sig);
            out[(size_t)t * (B_ * D_) + b * D_ + g * 8 + r] = o;   // plain cached
            float nb = __shfl_down(o, 1, 64);   // neighbor r+1 (same wave)
            if (!(r & 1))
                stcg_u(hx + b * (D_ / 2) + g * 4 + (r >> 1), packbf(o, nb));
        }
        flag_post(flagsB + g, (unsigned)(t + 1));   // h(t) published

        accP1 = accP1n; accG = accGn;
    }
}

extern "C" void kernel_launch(void* const* d_in, const int* in_sizes, int n_in,
                              void* d_out, int out_size, void* d_ws, size_t ws_size,
                              hipStream_t stream) {
    const float* x    = (const float*)d_in[0];
    const float* h0   = (const float*)d_in[1];
    const float* W1   = (const float*)d_in[2];
    const float* W2   = (const float*)d_in[3];
    const float* Wgx  = (const float*)d_in[4];
    const float* Wgh  = (const float*)d_in[5];
    const float* bias = (const float*)d_in[6];
    float* out = (float*)d_out;

    unsigned* flagsA = (unsigned*)d_ws;        // 128 u32
    unsigned* flagsB = flagsA + 128;           // 128 u32
    unsigned* hx     = flagsA + 1024;          // [B][D/2] = 32 KB (4KB-aligned)
    unsigned* hidx   = hx + B_ * (D_ / 2);     // [B][E/2] = 64 KB

    hipMemsetAsync(d_ws, 0, 4096, stream);     // zero flags every launch/replay

    hipFuncSetAttribute((const void*)elman5,
                        hipFuncAttributeMaxDynamicSharedMemorySize, LDS_BYTES);

    void* args[] = {(void*)&x, (void*)&h0, (void*)&W1, (void*)&W2,
                    (void*)&Wgx, (void*)&Wgh, (void*)&bias, (void*)&out,
                    (void*)&flagsA, (void*)&flagsB, (void*)&hx, (void*)&hidx};
    hipLaunchCooperativeKernel((const void*)elman5,
                               dim3(NWG), dim3(TPB), args,
                               (unsigned)LDS_BYTES, stream);
}

// Round 6
// 10203.168 us; speedup vs baseline: 1.1425x; 1.1425x over previous
//
#include <hip/hip_runtime.h>

// Problem sizes (fixed by the reference)
constexpr int D_ = 1024, E_ = 2048, B_ = 16, T_ = 1024;
constexpr int NWG = 128, TPB = 512;   // 128 WGs: 16 W1-rows, 8 W2/Wc/Wgx-rows each

typedef short bf16x8 __attribute__((ext_vector_type(8)));
typedef float f32x4  __attribute__((ext_vector_type(4)));

// ---- LDS byte offsets ----
constexpr int W1F   = 0;        // W1 frags:   64 kc * 1024 B = 64 KB
constexpr int W2CF  = 65536;    // [W2;Wc] frags: 64 kc * 1024 B = 64 KB
constexpr int WGXF  = 131072;   // Wgx compact frags: 32 kc * 512 B = 16 KB
constexpr int ZB    = 147456;   // 16 B zero block (gate cols 8..15)
constexpr int REDo  = 147472;   // 8 waves * 272 f32 (stride-17 rows)
constexpr int GREDo = 156176;   // 8 waves * 144 f32 (stride-9 rows)
constexpr int GPo   = 160784;   // 128 f32 gate-x partial (persists P1->P2)
constexpr int BIo   = 161296;   // 8 f32 bias slice
constexpr int LDS_BYTES = 161328;
static_assert(LDS_BYTES <= 163840, "LDS over 160KB");
constexpr int REDS = 272, GRS = 144;

// ---- device-coherent (LLC) helpers ----
__device__ __forceinline__ void stcg_u(unsigned* p, unsigned v) {
    __hip_atomic_store(p, v, __ATOMIC_RELAXED, __HIP_MEMORY_SCOPE_AGENT);
}
__device__ __forceinline__ uint2 ldcg_u2(const unsigned* p) {
    unsigned long long u = __hip_atomic_load((const unsigned long long*)p,
                                             __ATOMIC_RELAXED, __HIP_MEMORY_SCOPE_AGENT);
    uint2 r; __builtin_memcpy(&r, &u, 8); return r;
}

// ---- bf16 helpers ----
__device__ __forceinline__ unsigned f2bf(float f) {
    unsigned u; __builtin_memcpy(&u, &f, 4);
    u += 0x7fffu + ((u >> 16) & 1u);   // RNE
    return u >> 16;
}
__device__ __forceinline__ unsigned packbf(float lo, float hi) {
    return f2bf(lo) | (f2bf(hi) << 16);
}
__device__ __forceinline__ bf16x8 pack8(float4 a, float4 b) {
    union { unsigned short us[8]; bf16x8 v; } r;
    r.us[0] = (unsigned short)f2bf(a.x); r.us[1] = (unsigned short)f2bf(a.y);
    r.us[2] = (unsigned short)f2bf(a.z); r.us[3] = (unsigned short)f2bf(a.w);
    r.us[4] = (unsigned short)f2bf(b.x); r.us[5] = (unsigned short)f2bf(b.y);
    r.us[6] = (unsigned short)f2bf(b.z); r.us[7] = (unsigned short)f2bf(b.w);
    return r.v;
}
__device__ __forceinline__ bf16x8 frag_from(uint2 a, uint2 b) {
    union { unsigned u[4]; bf16x8 v; } r;
    r.u[0] = a.x; r.u[1] = a.y; r.u[2] = b.x; r.u[3] = b.y;
    return r.v;
}

// ---- publish: drain data stores, then post monotonic per-WG flag ----
__device__ __forceinline__ void flag_post(unsigned* flag, unsigned val) {
    asm volatile("s_waitcnt vmcnt(0)" ::: "memory");
    __syncthreads();
    if (threadIdx.x == 0) stcg_u(flag, val);
}

// ---- per-wave subset wait: lanes<8 each spin on one 8B flag pair ----
// Divergent spin: wave exits only when all 8 lanes saw their pair >= tgt.
// Relaxed polls (no cache maintenance); consumer data loads are uncached
// (agent scope), so flag-then-data is race-free: producer drained data to
// the coherence point before posting.
__device__ __forceinline__ void wait16(const unsigned* f, int off, unsigned tgt) {
    const int lane = threadIdx.x & 63;
    if (lane < 8) {
        const unsigned long long* p = (const unsigned long long*)(f + off);
        while (true) {
            unsigned long long u = __hip_atomic_load(
                p, __ATOMIC_RELAXED, __HIP_MEMORY_SCOPE_AGENT);
            if (((unsigned)u >= tgt) && ((unsigned)(u >> 32) >= tgt)) break;
            __builtin_amdgcn_s_sleep(1);
        }
    }
    asm volatile("" ::: "memory");   // compiler fence: no hoisting of data loads
}

__global__ void __launch_bounds__(TPB, 1)
elman6(const float* __restrict__ x, const float* __restrict__ h0,
       const float* __restrict__ W1, const float* __restrict__ W2g,
       const float* __restrict__ Wgx, const float* __restrict__ Wgh,
       const float* __restrict__ bias, float* __restrict__ out,
       unsigned* __restrict__ flagsA, unsigned* __restrict__ flagsB,
       unsigned* __restrict__ hxg  /* [128][16][4] u32: g-major carried h */,
       unsigned* __restrict__ hidg /* [128][16][8] u32: g-major hidden  */)
{
    extern __shared__ char sm[];
    float* REDF  = (float*)(sm + REDo);
    float* GREDF = (float*)(sm + GREDo);
    float* GPF   = (float*)(sm + GPo);
    float* BIF   = (float*)(sm + BIo);

    const int g = blockIdx.x, tid = threadIdx.x;
    const int l = tid & 63, wv = tid >> 6;   // lane, wave
    const int c16 = l & 15, q = l >> 4;      // frag col(batch) / k-octet group

    // ================= prologue: build bf16 fragment LDS =================
    {
        float* wght = (float*)(sm + W2CF);
        for (int i = tid; i < 8 * D_; i += TPB)
            wght[i] = Wgh[(size_t)(g * 8 + (i >> 10)) * D_ + (i & 1023)];
        if (tid < 8) BIF[tid] = bias[g * 8 + tid];
        if (tid == 0) *(float4*)(sm + ZB) = float4{0, 0, 0, 0};
        __syncthreads();

        // Wc = Wgh_slice @ W2  (f32, into W1F region)
        float* wcf = (float*)(sm + W1F);
        {
            const int k4 = tid * 4;
            float4 acc[8];
            #pragma unroll
            for (int r = 0; r < 8; ++r) acc[r] = float4{0, 0, 0, 0};
            const float* wp = W2g + k4;
            for (int m = 0; m < D_; ++m) {
                float4 wvv = *(const float4*)wp; wp += E_;
                #pragma unroll
                for (int r = 0; r < 8; ++r) {
                    float gm = wght[r * D_ + m];
                    acc[r].x = fmaf(gm, wvv.x, acc[r].x);
                    acc[r].y = fmaf(gm, wvv.y, acc[r].y);
                    acc[r].z = fmaf(gm, wvv.z, acc[r].z);
                    acc[r].w = fmaf(gm, wvv.w, acc[r].w);
                }
            }
            __syncthreads();
            #pragma unroll
            for (int r = 0; r < 8; ++r) *(float4*)(wcf + r * E_ + k4) = acc[r];
        }
        __syncthreads();

        // pack [W2;Wc] frags into W2CF
        for (int i = tid; i < 4096; i += TPB) {
            int kc = i >> 6, l2 = i & 63, cc = l2 & 15, qq = l2 >> 4;
            int k = kc * 32 + qq * 8;
            float4 lo, hi;
            if (cc < 8) {
                const float* src = W2g + (size_t)(g * 8 + cc) * E_ + k;
                lo = *(const float4*)src; hi = *(const float4*)(src + 4);
            } else {
                const float* src = wcf + (cc - 8) * E_ + k;
                lo = *(const float4*)src; hi = *(const float4*)(src + 4);
            }
            *(bf16x8*)(sm + W2CF + i * 16) = pack8(lo, hi);
        }
        __syncthreads();

        // pack W1 frags (16 rows, K=2048)
        for (int i = tid; i < 4096; i += TPB) {
            int kc = i >> 6, l2 = i & 63, cc = l2 & 15, qq = l2 >> 4;
            const float* src = W1 + (size_t)(g * 16 + cc) * (2 * D_) + kc * 32 + qq * 8;
            *(bf16x8*)(sm + W1F + i * 16) =
                pack8(*(const float4*)src, *(const float4*)(src + 4));
        }
        // pack Wgx compact frags (8 real cols only)
        for (int i = tid; i < 1024; i += TPB) {
            int kc = i >> 5, qq = (i >> 3) & 3, cc = i & 7;
            const float* src = Wgx + (size_t)(g * 8 + cc) * D_ + kc * 32 + qq * 8;
            *(bf16x8*)(sm + WGXF + kc * 512 + qq * 128 + cc * 16) =
                pack8(*(const float4*)src, *(const float4*)(src + 4));
        }
        __syncthreads();
    }

    const char* gz = sm + ZB;

    // ================= recurrence =================
    f32x4 accP1 = {0.f, 0.f, 0.f, 0.f}, accG = {0.f, 0.f, 0.f, 0.f};

    // x-work for t=0
    {
        #pragma unroll
        for (int i = 0; i < 4; ++i) {
            int kc = wv + i * 8;
            const float* xp = x + c16 * D_ + kc * 32 + q * 8;
            bf16x8 af = pack8(*(const float4*)xp, *(const float4*)(xp + 4));
            bf16x8 w1 = *(const bf16x8*)(sm + W1F + kc * 1024 + l * 16);
            accP1 = __builtin_amdgcn_mfma_f32_16x16x32_bf16(af, w1, accP1, 0, 0, 0);
            const char* ga = (c16 < 8) ? (sm + WGXF + kc * 512 + q * 128 + c16 * 16) : gz;
            bf16x8 wg = *(const bf16x8*)ga;
            accG = __builtin_amdgcn_mfma_f32_16x16x32_bf16(af, wg, accG, 0, 0, 0);
        }
    }

    for (int t = 0; t < T_; ++t) {
        // ---- P1 h-part: 4 chunks, per-wave dataflow waits on 16 producers
        if (t == 0) {
            #pragma unroll
            for (int i = 0; i < 4; ++i) {
                int kc = 32 + wv + i * 8;
                const float* hp = h0 + c16 * D_ + (kc - 32) * 32 + q * 8;
                bf16x8 af = pack8(*(const float4*)hp, *(const float4*)(hp + 4));
                bf16x8 w1 = *(const bf16x8*)(sm + W1F + kc * 1024 + l * 16);
                accP1 = __builtin_amdgcn_mfma_f32_16x16x32_bf16(af, w1, accP1, 0, 0, 0);
            }
        } else {
            // owners for chunk i: 4*(wv+8i)+{0..3}; lane L<8 polls pair
            wait16(flagsB, 4 * wv + 32 * ((l & 7) >> 1) + 2 * (l & 1), (unsigned)t);
            #pragma unroll
            for (int i = 0; i < 4; ++i) {
                int kk = wv + i * 8;
                const unsigned* hp = hxg + ((4 * kk + q) * 16 + c16) * 4;
                bf16x8 af = frag_from(ldcg_u2(hp), ldcg_u2(hp + 2));
                bf16x8 w1 = *(const bf16x8*)(sm + W1F + (32 + kk) * 1024 + l * 16);
                accP1 = __builtin_amdgcn_mfma_f32_16x16x32_bf16(af, w1, accP1, 0, 0, 0);
            }
        }

        // ---- reduce P1 + gate partials across waves
        #pragma unroll
        for (int i = 0; i < 4; ++i)
            REDF[wv * REDS + (q * 4 + i) * 17 + c16] = accP1[i];
        if (c16 < 8) {
            #pragma unroll
            for (int i = 0; i < 4; ++i)
                GREDF[wv * GRS + (q * 4 + i) * 9 + c16] = accG[i];
        }
        __syncthreads();
        if (tid < 256) {                 // hidden = tanh(sum); coalesced publish
            int b = tid >> 4, wr = tid & 15;
            float s = 0;
            #pragma unroll
            for (int w = 0; w < 8; ++w) s += REDF[w * REDS + b * 17 + wr];
            float tv = tanhf(s);
            float nb = __shfl_down(tv, 1, 64);
            if (!(wr & 1))
                stcg_u(hidg + (g * 16 + b) * 8 + (wr >> 1), packbf(tv, nb));
        } else if (tid < 384) {          // gate-x partial -> LDS (read in P2)
            int gt = tid - 256, b = gt >> 3, rp = gt & 7;
            float s = 0;
            #pragma unroll
            for (int w = 0; w < 8; ++w) s += GREDF[w * GRS + b * 9 + rp];
            GPF[gt] = s;
        }
        flag_post(flagsA + g, (unsigned)(t + 1));   // hidden published

        // ---- x-work for t+1 (fills the wait window)
        f32x4 accP1n = {0.f, 0.f, 0.f, 0.f}, accGn = {0.f, 0.f, 0.f, 0.f};
        if (t + 1 < T_) {
            const float* xt = x + (size_t)(t + 1) * (B_ * D_);
            #pragma unroll
            for (int i = 0; i < 4; ++i) {
                int kc = wv + i * 8;
                const float* xp = xt + c16 * D_ + kc * 32 + q * 8;
                bf16x8 af = pack8(*(const float4*)xp, *(const float4*)(xp + 4));
                bf16x8 w1 = *(const bf16x8*)(sm + W1F + kc * 1024 + l * 16);
                accP1n = __builtin_amdgcn_mfma_f32_16x16x32_bf16(af, w1, accP1n, 0, 0, 0);
                const char* ga = (c16 < 8) ? (sm + WGXF + kc * 512 + q * 128 + c16 * 16) : gz;
                bf16x8 wg = *(const bf16x8*)ga;
                accGn = __builtin_amdgcn_mfma_f32_16x16x32_bf16(af, wg, accGn, 0, 0, 0);
            }
        }

        // ---- P2: per-wave dataflow wait (owners 2kc,2kc+1 per chunk)
        wait16(flagsA, 2 * wv + 16 * (l & 7), (unsigned)(t + 1));
        f32x4 acc2 = {0.f, 0.f, 0.f, 0.f};
        #pragma unroll
        for (int i = 0; i < 8; ++i) {
            int kc = wv + i * 8;
            const unsigned* hp = hidg + ((2 * kc + (q >> 1)) * 16 + c16) * 8 + (q & 1) * 4;
            bf16x8 af = frag_from(ldcg_u2(hp), ldcg_u2(hp + 2));
            bf16x8 w2 = *(const bf16x8*)(sm + W2CF + kc * 1024 + l * 16);
            acc2 = __builtin_amdgcn_mfma_f32_16x16x32_bf16(af, w2, acc2, 0, 0, 0);
        }
        #pragma unroll
        for (int i = 0; i < 4; ++i)
            REDF[wv * REDS + (q * 4 + i) * 17 + c16] = acc2[i];
        __syncthreads();
        if (tid < 128) {                 // finalize out = hnew * silu(u); publish h
            int b = tid >> 3, r = tid & 7;
            float hn = 0, uv = 0;
            #pragma unroll
            for (int w = 0; w < 8; ++w) {
                hn += REDF[w * REDS + b * 17 + r];
                uv += REDF[w * REDS + b * 17 + 8 + r];
            }
            uv += GPF[b * 8 + r] + BIF[r];
            float sig = 1.0f / (1.0f + __expf(-uv));
            float o = hn * (uv * sig);
            out[(size_t)t * (B_ * D_) + b * D_ + g * 8 + r] = o;   // plain cached
            float nb = __shfl_down(o, 1, 64);
            if (!(r & 1))
                stcg_u(hxg + (g * 16 + b) * 4 + (r >> 1), packbf(o, nb));
        }
        flag_post(flagsB + g, (unsigned)(t + 1));   // h(t) published

        accP1 = accP1n; accG = accGn;
    }
}

extern "C" void kernel_launch(void* const* d_in, const int* in_sizes, int n_in,
                              void* d_out, int out_size, void* d_ws, size_t ws_size,
                              hipStream_t stream) {
    const float* x    = (const float*)d_in[0];
    const float* h0   = (const float*)d_in[1];
    const float* W1   = (const float*)d_in[2];
    const float* W2   = (const float*)d_in[3];
    const float* Wgx  = (const float*)d_in[4];
    const float* Wgh  = (const float*)d_in[5];
    const float* bias = (const float*)d_in[6];
    float* out = (float*)d_out;

    unsigned* flagsA = (unsigned*)d_ws;          // 128 u32
    unsigned* flagsB = flagsA + 256;             // 128 u32 (1KB apart)
    unsigned* hidg   = (unsigned*)((char*)d_ws + 4096);   // [128][16][8] = 64KB
    unsigned* hxg    = hidg + 128 * 16 * 8;                // [128][16][4] = 32KB

    hipMemsetAsync(d_ws, 0, 4096, stream);       // zero flags every launch/replay

    hipFuncSetAttribute((const void*)elman6,
                        hipFuncAttributeMaxDynamicSharedMemorySize, LDS_BYTES);

    void* args[] = {(void*)&x, (void*)&h0, (void*)&W1, (void*)&W2,
                    (void*)&Wgx, (void*)&Wgh, (void*)&bias, (void*)&out,
                    (void*)&flagsA, (void*)&flagsB, (void*)&hxg, (void*)&hidg};
    hipLaunchCooperativeKernel((const void*)elman6,
                               dim3(NWG), dim3(TPB), args,
                               (unsigned)LDS_BYTES, stream);
}

// Round 7
// 6826.839 us; speedup vs baseline: 1.7076x; 1.4946x over previous
//
#include <hip/hip_runtime.h>

// Problem sizes (fixed by the reference)
constexpr int D_ = 1024, E_ = 2048, B_ = 16, T_ = 1024;
constexpr int NWG = 128, TPB = 512;   // 128 WGs: 16 W1-rows, 8 W2/Wc/Wgx-rows each

typedef short bf16x8 __attribute__((ext_vector_type(8)));
typedef float f32x4  __attribute__((ext_vector_type(4)));

// ---- LDS byte offsets ----
constexpr int W1F   = 0;                 // W1 frags: 64 kc * 1024 B
constexpr int W2CF  = 65536;             // [W2;Wc] frags: 64 kc * 1024 B
constexpr int WGXF  = 131072;            // Wgx compact frags: 16 KB
constexpr int ZB    = 147456;            // 16 B zero block
constexpr int REDo  = 147472;            // 8 waves * 260 f32 = 8320 B (linear [w][e])
constexpr int GREDo = REDo + 8320;       // 8 waves * 136 f32 = 4352 B
constexpr int GPo   = GREDo + 4352;      // 128 f32 gate-x partial
constexpr int BIo   = GPo + 512;         // 8 f32 bias slice
constexpr int LDS_BYTES = BIo + 32;
static_assert(LDS_BYTES <= 163840, "LDS over 160KB");
constexpr int REDS = 260, GRS = 136;     // per-wave strides (floats)

// ---- device-coherent (IF$) helpers ----
__device__ __forceinline__ void stcg_u(unsigned* p, unsigned v) {
    __hip_atomic_store(p, v, __ATOMIC_RELAXED, __HIP_MEMORY_SCOPE_AGENT);
}
__device__ __forceinline__ uint2 ldcg_u2(const unsigned* p) {
    unsigned long long u = __hip_atomic_load((const unsigned long long*)p,
                                             __ATOMIC_RELAXED, __HIP_MEMORY_SCOPE_AGENT);
    uint2 r; __builtin_memcpy(&r, &u, 8); return r;
}

// ---- bf16 helpers ----
__device__ __forceinline__ unsigned f2bf(float f) {
    unsigned u; __builtin_memcpy(&u, &f, 4);
    u += 0x7fffu + ((u >> 16) & 1u);   // RNE
    return u >> 16;
}
__device__ __forceinline__ unsigned packbf(float lo, float hi) {
    return f2bf(lo) | (f2bf(hi) << 16);
}
__device__ __forceinline__ bf16x8 pack8(float4 a, float4 b) {
    union { unsigned short us[8]; bf16x8 v; } r;
    r.us[0] = (unsigned short)f2bf(a.x); r.us[1] = (unsigned short)f2bf(a.y);
    r.us[2] = (unsigned short)f2bf(a.z); r.us[3] = (unsigned short)f2bf(a.w);
    r.us[4] = (unsigned short)f2bf(b.x); r.us[5] = (unsigned short)f2bf(b.y);
    r.us[6] = (unsigned short)f2bf(b.z); r.us[7] = (unsigned short)f2bf(b.w);
    return r.v;
}
__device__ __forceinline__ bf16x8 frag_from(uint2 a, uint2 b) {
    union { unsigned u[4]; bf16x8 v; } r;
    r.u[0] = a.x; r.u[1] = a.y; r.u[2] = b.x; r.u[3] = b.y;
    return r.v;
}

// ---- per-wave subset wait: lanes<16 each BUSY-poll one 64B-strided flag ----
// Busy spin (no s_sleep) with a dependent-FMA backoff chain: keeps the SIMDs
// issuing (DVFS stays at high clock) and throttles IF$ poll traffic to ~1
// load / ~300ns / lane. Flag-then-data is race-free as in r6: producer
// drains exchange stores to the coherence point before posting; consumer
// data loads are agent-scope (L1/L2-bypassing).
__device__ __forceinline__ void wait16b(const unsigned* f, int owner, unsigned tgt) {
    const int lane = threadIdx.x & 63;
    if (lane < 16) {
        const unsigned* p = f + owner * 16;   // 64 B stride
        float a = 1.0000001f, c = 0.9999999f;
        while (__hip_atomic_load(p, __ATOMIC_RELAXED, __HIP_MEMORY_SCOPE_AGENT) < tgt) {
            #pragma unroll
            for (int i = 0; i < 16; ++i) {
                a = __builtin_fmaf(a, c, 1e-30f);
                c = __builtin_fmaf(c, a, -1e-30f);
            }
            asm volatile("" : "+v"(a), "+v"(c));   // keep the chain alive
        }
    }
    asm volatile("" ::: "memory");   // no hoisting of data loads above the poll
}

__global__ void __launch_bounds__(TPB, 1)
elman7(const float* __restrict__ x, const float* __restrict__ h0,
       const float* __restrict__ W1, const float* __restrict__ W2g,
       const float* __restrict__ Wgx, const float* __restrict__ Wgh,
       const float* __restrict__ bias, float* __restrict__ out,
       unsigned* __restrict__ flagsA, unsigned* __restrict__ flagsB,
       unsigned* __restrict__ hxg  /* [128][16][4] u32: g-major carried h */,
       unsigned* __restrict__ hidg /* [128][16][8] u32: g-major hidden  */)
{
    extern __shared__ char sm[];
    float* REDF  = (float*)(sm + REDo);
    float* GREDF = (float*)(sm + GREDo);
    float* GPF   = (float*)(sm + GPo);
    float* BIF   = (float*)(sm + BIo);

    const int g = blockIdx.x, tid = threadIdx.x;
    const int l = tid & 63, wv = tid >> 6;   // lane, wave
    const int c16 = l & 15, q = l >> 4;      // frag col(batch-ish) / k-octet group

    // ================= prologue: build bf16 fragment LDS =================
    {
        float* wght = (float*)(sm + W2CF);
        for (int i = tid; i < 8 * D_; i += TPB)
            wght[i] = Wgh[(size_t)(g * 8 + (i >> 10)) * D_ + (i & 1023)];
        if (tid < 8) BIF[tid] = bias[g * 8 + tid];
        if (tid == 0) *(float4*)(sm + ZB) = float4{0, 0, 0, 0};
        __syncthreads();

        // Wc = Wgh_slice @ W2  (f32, into W1F region)
        float* wcf = (float*)(sm + W1F);
        {
            const int k4 = tid * 4;
            float4 acc[8];
            #pragma unroll
            for (int r = 0; r < 8; ++r) acc[r] = float4{0, 0, 0, 0};
            const float* wp = W2g + k4;
            for (int m = 0; m < D_; ++m) {
                float4 wvv = *(const float4*)wp; wp += E_;
                #pragma unroll
                for (int r = 0; r < 8; ++r) {
                    float gm = wght[r * D_ + m];
                    acc[r].x = fmaf(gm, wvv.x, acc[r].x);
                    acc[r].y = fmaf(gm, wvv.y, acc[r].y);
                    acc[r].z = fmaf(gm, wvv.z, acc[r].z);
                    acc[r].w = fmaf(gm, wvv.w, acc[r].w);
                }
            }
            __syncthreads();
            #pragma unroll
            for (int r = 0; r < 8; ++r) *(float4*)(wcf + r * E_ + k4) = acc[r];
        }
        __syncthreads();

        // pack [W2;Wc] frags into W2CF
        for (int i = tid; i < 4096; i += TPB) {
            int kc = i >> 6, l2 = i & 63, cc = l2 & 15, qq = l2 >> 4;
            int k = kc * 32 + qq * 8;
            float4 lo, hi;
            if (cc < 8) {
                const float* src = W2g + (size_t)(g * 8 + cc) * E_ + k;
                lo = *(const float4*)src; hi = *(const float4*)(src + 4);
            } else {
                const float* src = wcf + (cc - 8) * E_ + k;
                lo = *(const float4*)src; hi = *(const float4*)(src + 4);
            }
            *(bf16x8*)(sm + W2CF + i * 16) = pack8(lo, hi);
        }
        __syncthreads();

        // pack W1 frags (16 rows, K=2048)
        for (int i = tid; i < 4096; i += TPB) {
            int kc = i >> 6, l2 = i & 63, cc = l2 & 15, qq = l2 >> 4;
            const float* src = W1 + (size_t)(g * 16 + cc) * (2 * D_) + kc * 32 + qq * 8;
            *(bf16x8*)(sm + W1F + i * 16) =
                pack8(*(const float4*)src, *(const float4*)(src + 4));
        }
        // pack Wgx compact frags (8 real cols only)
        for (int i = tid; i < 1024; i += TPB) {
            int kc = i >> 5, qq = (i >> 3) & 3, cc = i & 7;
            const float* src = Wgx + (size_t)(g * 8 + cc) * D_ + kc * 32 + qq * 8;
            *(bf16x8*)(sm + WGXF + kc * 512 + qq * 128 + cc * 16) =
                pack8(*(const float4*)src, *(const float4*)(src + 4));
        }
        __syncthreads();
    }

    const char* gz = sm + ZB;

    // ================= recurrence =================
    f32x4 accP1 = {0.f, 0.f, 0.f, 0.f}, accG = {0.f, 0.f, 0.f, 0.f};

    // x-work for t=0
    {
        #pragma unroll
        for (int i = 0; i < 4; ++i) {
            int kc = wv + i * 8;
            const float* xp = x + c16 * D_ + kc * 32 + q * 8;
            bf16x8 af = pack8(*(const float4*)xp, *(const float4*)(xp + 4));
            bf16x8 w1 = *(const bf16x8*)(sm + W1F + kc * 1024 + l * 16);
            accP1 = __builtin_amdgcn_mfma_f32_16x16x32_bf16(af, w1, accP1, 0, 0, 0);
            const char* ga = (c16 < 8) ? (sm + WGXF + kc * 512 + q * 128 + c16 * 16) : gz;
            bf16x8 wg = *(const bf16x8*)ga;
            accG = __builtin_amdgcn_mfma_f32_16x16x32_bf16(af, wg, accG, 0, 0, 0);
        }
    }

    for (int t = 0; t < T_; ++t) {
        // ---- P1 h-part: per-wave subset wait + 4 chunks
        if (t == 0) {
            #pragma unroll
            for (int i = 0; i < 4; ++i) {
                int kc = 32 + wv + i * 8;
                const float* hp = h0 + c16 * D_ + (kc - 32) * 32 + q * 8;
                bf16x8 af = pack8(*(const float4*)hp, *(const float4*)(hp + 4));
                bf16x8 w1 = *(const bf16x8*)(sm + W1F + kc * 1024 + l * 16);
                accP1 = __builtin_amdgcn_mfma_f32_16x16x32_bf16(af, w1, accP1, 0, 0, 0);
            }
        } else {
            wait16b(flagsB, 4 * wv + 32 * (l >> 2) + (l & 3), (unsigned)t);
            #pragma unroll
            for (int i = 0; i < 4; ++i) {
                int kk = wv + i * 8;
                const unsigned* hp = hxg + ((4 * kk + q) * 16 + c16) * 4;
                bf16x8 af = frag_from(ldcg_u2(hp), ldcg_u2(hp + 2));
                bf16x8 w1 = *(const bf16x8*)(sm + W1F + (32 + kk) * 1024 + l * 16);
                accP1 = __builtin_amdgcn_mfma_f32_16x16x32_bf16(af, w1, accP1, 0, 0, 0);
            }
        }

        // ---- reduce P1 + gate partials (linear [w][e] layout, e = b*16+row)
        #pragma unroll
        for (int i = 0; i < 4; ++i)
            REDF[wv * REDS + (q * 4 + i) * 16 + c16] = accP1[i];
        if (c16 < 8) {
            #pragma unroll
            for (int i = 0; i < 4; ++i)
                GREDF[wv * GRS + (q * 4 + i) * 8 + c16] = accG[i];
        }
        __syncthreads();
        float4 hsum;
        if (wv == 0) {             // wave 0: conflict-free float4 sums
            hsum = *(const float4*)(REDF + 4 * l);
            #pragma unroll
            for (int w = 1; w < 8; ++w) {
                float4 v = *(const float4*)(REDF + w * REDS + 4 * l);
                hsum.x += v.x; hsum.y += v.y; hsum.z += v.z; hsum.w += v.w;
            }
        } else if (wv == 1 || wv == 2) {   // waves 1-2: gate-x partial -> GPF
            int gt = (wv - 1) * 64 + l;
            float s = 0;
            #pragma unroll
            for (int w = 0; w < 8; ++w) s += GREDF[w * GRS + gt];
            GPF[gt] = s;
        }
        __syncthreads();           // REDF free for P2; GPF published (read later)
        if (wv == 0) {             // wave 0: tanh + coalesced publish + early flag
            float t0 = tanhf(hsum.x), t1 = tanhf(hsum.y);
            float t2 = tanhf(hsum.z), t3 = tanhf(hsum.w);
            unsigned* dst = hidg + ((g * 16 + (l >> 2)) * 8) + 2 * (l & 3);
            stcg_u(dst,     packbf(t0, t1));
            stcg_u(dst + 1, packbf(t2, t3));
            asm volatile("s_waitcnt vmcnt(0)" ::: "memory");
            if (l == 0) stcg_u(flagsA + g * 16, (unsigned)(t + 1));
        }

        // ---- x-work for t+1 (waves 1-7 start immediately; wave 0 after post)
        f32x4 accP1n = {0.f, 0.f, 0.f, 0.f}, accGn = {0.f, 0.f, 0.f, 0.f};
        if (t + 1 < T_) {
            const float* xt = x + (size_t)(t + 1) * (B_ * D_);
            #pragma unroll
            for (int i = 0; i < 4; ++i) {
                int kc = wv + i * 8;
                const float* xp = xt + c16 * D_ + kc * 32 + q * 8;
                bf16x8 af = pack8(*(const float4*)xp, *(const float4*)(xp + 4));
                bf16x8 w1 = *(const bf16x8*)(sm + W1F + kc * 1024 + l * 16);
                accP1n = __builtin_amdgcn_mfma_f32_16x16x32_bf16(af, w1, accP1n, 0, 0, 0);
                const char* ga = (c16 < 8) ? (sm + WGXF + kc * 512 + q * 128 + c16 * 16) : gz;
                bf16x8 wg = *(const bf16x8*)ga;
                accGn = __builtin_amdgcn_mfma_f32_16x16x32_bf16(af, wg, accGn, 0, 0, 0);
            }
        }

        // ---- P2: per-wave subset wait + 8 chunks
        wait16b(flagsA, 2 * wv + 16 * (l >> 1) + (l & 1), (unsigned)(t + 1));
        f32x4 acc2 = {0.f, 0.f, 0.f, 0.f};
        #pragma unroll
        for (int i = 0; i < 8; ++i) {
            int kc = wv + i * 8;
            const unsigned* hp = hidg + ((2 * kc + (q >> 1)) * 16 + c16) * 8 + (q & 1) * 4;
            bf16x8 af = frag_from(ldcg_u2(hp), ldcg_u2(hp + 2));
            bf16x8 w2 = *(const bf16x8*)(sm + W2CF + kc * 1024 + l * 16);
            acc2 = __builtin_amdgcn_mfma_f32_16x16x32_bf16(af, w2, acc2, 0, 0, 0);
        }
        #pragma unroll
        for (int i = 0; i < 4; ++i)
            REDF[wv * REDS + (q * 4 + i) * 16 + c16] = acc2[i];
        __syncthreads();
        float4 s4 = {0.f, 0.f, 0.f, 0.f};
        if (wv == 0) {             // wave 0: float4 sums (e = b*16 + rr)
            #pragma unroll
            for (int w = 0; w < 8; ++w) {
                float4 v = *(const float4*)(REDF + w * REDS + 4 * l);
                s4.x += v.x; s4.y += v.y; s4.z += v.z; s4.w += v.w;
            }
        }
        __syncthreads();           // REDF free for next-step P1
        if (wv == 0) {             // finalize: hn lanes (l&3)<2, u from lane l+2
            float4 u4;
            u4.x = __shfl(s4.x, l + 2, 64); u4.y = __shfl(s4.y, l + 2, 64);
            u4.z = __shfl(s4.z, l + 2, 64); u4.w = __shfl(s4.w, l + 2, 64);
            if ((l & 3) < 2) {
                int b = l >> 2, r0 = 4 * (l & 3);
                float oo[4];
                #pragma unroll
                for (int j = 0; j < 4; ++j) {
                    float hn = (j == 0) ? s4.x : (j == 1) ? s4.y : (j == 2) ? s4.z : s4.w;
                    float uj = (j == 0) ? u4.x : (j == 1) ? u4.y : (j == 2) ? u4.z : u4.w;
                    float uv = uj + GPF[b * 8 + r0 + j] + BIF[r0 + j];
                    float sig = 1.0f / (1.0f + __expf(-uv));
                    oo[j] = hn * (uv * sig);
                }
                *(float4*)(out + (size_t)t * (B_ * D_) + b * D_ + g * 8 + r0) =
                    float4{oo[0], oo[1], oo[2], oo[3]};
                unsigned* hdst = hxg + ((g * 16 + b) * 4) + (r0 >> 1);
                stcg_u(hdst,     packbf(oo[0], oo[1]));
                stcg_u(hdst + 1, packbf(oo[2], oo[3]));
            }
            asm volatile("s_waitcnt vmcnt(0)" ::: "memory");
            if (l == 0) stcg_u(flagsB + g * 16, (unsigned)(t + 1));
        }

        accP1 = accP1n; accG = accGn;
    }
}

extern "C" void kernel_launch(void* const* d_in, const int* in_sizes, int n_in,
                              void* d_out, int out_size, void* d_ws, size_t ws_size,
                              hipStream_t stream) {
    const float* x    = (const float*)d_in[0];
    const float* h0   = (const float*)d_in[1];
    const float* W1   = (const float*)d_in[2];
    const float* W2   = (const float*)d_in[3];
    const float* Wgx  = (const float*)d_in[4];
    const float* Wgh  = (const float*)d_in[5];
    const float* bias = (const float*)d_in[6];
    float* out = (float*)d_out;

    unsigned* flagsA = (unsigned*)d_ws;            // 128 flags, 64B stride = 8KB
    unsigned* flagsB = flagsA + 2048;              // 8KB
    unsigned* hidg   = (unsigned*)((char*)d_ws + 16384);  // [128][16][8] = 64KB
    unsigned* hxg    = hidg + 128 * 16 * 8;                // [128][16][4] = 32KB

    hipMemsetAsync(d_ws, 0, 16384, stream);        // zero flags every launch/replay

    hipFuncSetAttribute((const void*)elman7,
                        hipFuncAttributeMaxDynamicSharedMemorySize, LDS_BYTES);

    void* args[] = {(void*)&x, (void*)&h0, (void*)&W1, (void*)&W2,
                    (void*)&Wgx, (void*)&Wgh, (void*)&bias, (void*)&out,
                    (void*)&flagsA, (void*)&flagsB, (void*)&hxg, (void*)&hidg};
    hipLaunchCooperativeKernel((const void*)elman7,
                               dim3(NWG), dim3(TPB), args,
                               (unsigned)LDS_BYTES, stream);
}

// Round 8
// 6495.305 us; speedup vs baseline: 1.7947x; 1.0510x over previous
//
#include <hip/hip_runtime.h>

// Problem sizes (fixed by the reference)
constexpr int D_ = 1024, E_ = 2048, B_ = 16, T_ = 1024;
constexpr int NWG = 128, TPB = 512;   // 128 WGs: 16 W1-rows, 8 W2/Wc/Wgx-rows each

typedef short bf16x8 __attribute__((ext_vector_type(8)));
typedef float f32x4  __attribute__((ext_vector_type(4)));
typedef unsigned u32x4 __attribute__((ext_vector_type(4)));

constexpr unsigned POIS = 0xFFFFFFFFu;   // impossible as (finite bf16, finite bf16) pair

// ---- LDS byte offsets ----
constexpr int W1F   = 0;                 // W1 frags: 64 kc * 1024 B
constexpr int W2CF  = 65536;             // [W2;Wc] frags: 64 kc * 1024 B
constexpr int WGXF  = 131072;            // Wgx compact frags: 16 KB
constexpr int ZB    = 147456;            // 16 B zero block
constexpr int REDo  = 147472;            // 8 waves * 260 f32 (linear [w][e])
constexpr int GREDo = REDo + 8320;       // 8 waves * 136 f32
constexpr int GPo   = GREDo + 4352;      // 128 f32 gate-x partial
constexpr int BIo   = GPo + 512;         // 8 f32 bias slice
constexpr int LDS_BYTES = BIo + 32;
static_assert(LDS_BYTES <= 163840, "LDS over 160KB");
constexpr int REDS = 260, GRS = 136;

// ---- device-coherent (IF$) helpers ----
__device__ __forceinline__ void stcg_u(unsigned* p, unsigned v) {
    __hip_atomic_store(p, v, __ATOMIC_RELAXED, __HIP_MEMORY_SCOPE_AGENT);
}

// uncached 16B load (bypasses L1/L2 -> reads the coherence point)
__device__ __forceinline__ u32x4 ld1(const unsigned* p) {
    u32x4 r;
    asm volatile("global_load_dwordx4 %0, %1, off sc0 sc1\n\t"
                 "s_waitcnt vmcnt(0)"
                 : "=&v"(r) : "v"(p) : "memory");
    return r;
}
// four pipelined uncached 16B loads, single wait
__device__ __forceinline__ void ld4(const unsigned* p0, const unsigned* p1,
                                    const unsigned* p2, const unsigned* p3,
                                    u32x4& a, u32x4& b, u32x4& c, u32x4& d) {
    asm volatile("global_load_dwordx4 %0, %4, off sc0 sc1\n\t"
                 "global_load_dwordx4 %1, %5, off sc0 sc1\n\t"
                 "global_load_dwordx4 %2, %6, off sc0 sc1\n\t"
                 "global_load_dwordx4 %3, %7, off sc0 sc1\n\t"
                 "s_waitcnt vmcnt(0)"
                 : "=&v"(a), "=&v"(b), "=&v"(c), "=&v"(d)
                 : "v"(p0), "v"(p1), "v"(p2), "v"(p3) : "memory");
}
__device__ __forceinline__ bool bad4(u32x4 u) {
    return (u.x == POIS) || (u.y == POIS) || (u.z == POIS) || (u.w == POIS);
}

// ---- bf16 helpers ----
__device__ __forceinline__ unsigned f2bf(float f) {
    unsigned u; __builtin_memcpy(&u, &f, 4);
    u += 0x7fffu + ((u >> 16) & 1u);   // RNE
    return u >> 16;
}
__device__ __forceinline__ unsigned packbf(float lo, float hi) {
    return f2bf(lo) | (f2bf(hi) << 16);
}
__device__ __forceinline__ bf16x8 pack8(float4 a, float4 b) {
    union { unsigned short us[8]; bf16x8 v; } r;
    r.us[0] = (unsigned short)f2bf(a.x); r.us[1] = (unsigned short)f2bf(a.y);
    r.us[2] = (unsigned short)f2bf(a.z); r.us[3] = (unsigned short)f2bf(a.w);
    r.us[4] = (unsigned short)f2bf(b.x); r.us[5] = (unsigned short)f2bf(b.y);
    r.us[6] = (unsigned short)f2bf(b.z); r.us[7] = (unsigned short)f2bf(b.w);
    return r.v;
}
__device__ __forceinline__ bf16x8 fragu(u32x4 u) {
    union { u32x4 a; bf16x8 v; } r; r.a = u; return r.v;
}

__global__ void __launch_bounds__(TPB, 1)
elman8(const float* __restrict__ x, const float* __restrict__ h0,
       const float* __restrict__ W1, const float* __restrict__ W2g,
       const float* __restrict__ Wgx, const float* __restrict__ Wgh,
       const float* __restrict__ bias, float* __restrict__ out,
       unsigned* __restrict__ hxg  /* 3 slots x [128][16][4] u32 */,
       unsigned* __restrict__ hidg /* 3 slots x [128][16][8] u32 */)
{
    extern __shared__ char sm[];
    float* REDF  = (float*)(sm + REDo);
    float* GREDF = (float*)(sm + GREDo);
    float* GPF   = (float*)(sm + GPo);
    float* BIF   = (float*)(sm + BIo);

    const int g = blockIdx.x, tid = threadIdx.x;
    const int l = tid & 63, wv = tid >> 6;   // lane, wave
    const int c16 = l & 15, q = l >> 4;      // frag col(batch) / k-octet group

    // ================= prologue: build bf16 fragment LDS =================
    {
        float* wght = (float*)(sm + W2CF);
        for (int i = tid; i < 8 * D_; i += TPB)
            wght[i] = Wgh[(size_t)(g * 8 + (i >> 10)) * D_ + (i & 1023)];
        if (tid < 8) BIF[tid] = bias[g * 8 + tid];
        if (tid == 0) *(float4*)(sm + ZB) = float4{0, 0, 0, 0};
        __syncthreads();

        // Wc = Wgh_slice @ W2  (f32, into W1F region)
        float* wcf = (float*)(sm + W1F);
        {
            const int k4 = tid * 4;
            float4 acc[8];
            #pragma unroll
            for (int r = 0; r < 8; ++r) acc[r] = float4{0, 0, 0, 0};
            const float* wp = W2g + k4;
            for (int m = 0; m < D_; ++m) {
                float4 wvv = *(const float4*)wp; wp += E_;
                #pragma unroll
                for (int r = 0; r < 8; ++r) {
                    float gm = wght[r * D_ + m];
                    acc[r].x = fmaf(gm, wvv.x, acc[r].x);
                    acc[r].y = fmaf(gm, wvv.y, acc[r].y);
                    acc[r].z = fmaf(gm, wvv.z, acc[r].z);
                    acc[r].w = fmaf(gm, wvv.w, acc[r].w);
                }
            }
            __syncthreads();
            #pragma unroll
            for (int r = 0; r < 8; ++r) *(float4*)(wcf + r * E_ + k4) = acc[r];
        }
        __syncthreads();

        // pack [W2;Wc] frags into W2CF
        for (int i = tid; i < 4096; i += TPB) {
            int kc = i >> 6, l2 = i & 63, cc = l2 & 15, qq = l2 >> 4;
            int k = kc * 32 + qq * 8;
            float4 lo, hi;
            if (cc < 8) {
                const float* src = W2g + (size_t)(g * 8 + cc) * E_ + k;
                lo = *(const float4*)src; hi = *(const float4*)(src + 4);
            } else {
                const float* src = wcf + (cc - 8) * E_ + k;
                lo = *(const float4*)src; hi = *(const float4*)(src + 4);
            }
            *(bf16x8*)(sm + W2CF + i * 16) = pack8(lo, hi);
        }
        __syncthreads();

        // pack W1 frags (16 rows, K=2048)
        for (int i = tid; i < 4096; i += TPB) {
            int kc = i >> 6, l2 = i & 63, cc = l2 & 15, qq = l2 >> 4;
            const float* src = W1 + (size_t)(g * 16 + cc) * (2 * D_) + kc * 32 + qq * 8;
            *(bf16x8*)(sm + W1F + i * 16) =
                pack8(*(const float4*)src, *(const float4*)(src + 4));
        }
        // pack Wgx compact frags (8 real cols only)
        for (int i = tid; i < 1024; i += TPB) {
            int kc = i >> 5, qq = (i >> 3) & 3, cc = i & 7;
            const float* src = Wgx + (size_t)(g * 8 + cc) * D_ + kc * 32 + qq * 8;
            *(bf16x8*)(sm + WGXF + kc * 512 + qq * 128 + cc * 16) =
                pack8(*(const float4*)src, *(const float4*)(src + 4));
        }
        __syncthreads();
    }

    const char* gz = sm + ZB;

    // ================= recurrence =================
    f32x4 accP1 = {0.f, 0.f, 0.f, 0.f}, accG = {0.f, 0.f, 0.f, 0.f};

    // x-work for t=0
    {
        #pragma unroll
        for (int i = 0; i < 4; ++i) {
            int kc = wv + i * 8;
            const float* xp = x + c16 * D_ + kc * 32 + q * 8;
            bf16x8 af = pack8(*(const float4*)xp, *(const float4*)(xp + 4));
            bf16x8 w1 = *(const bf16x8*)(sm + W1F + kc * 1024 + l * 16);
            accP1 = __builtin_amdgcn_mfma_f32_16x16x32_bf16(af, w1, accP1, 0, 0, 0);
            const char* ga = (c16 < 8) ? (sm + WGXF + kc * 512 + q * 128 + c16 * 16) : gz;
            bf16x8 wg = *(const bf16x8*)ga;
            accG = __builtin_amdgcn_mfma_f32_16x16x32_bf16(af, wg, accG, 0, 0, 0);
        }
    }

    int sW = 0, sP = 1, sR = 2;   // write / poison-next / read(h of t-1) slots

    for (int t = 0; t < T_; ++t) {
        // ================ A: P1 h-part (self-validating poll loads) ================
        if (t == 0) {
            #pragma unroll
            for (int i = 0; i < 4; ++i) {
                int kc = 32 + wv + i * 8;
                const float* hp = h0 + c16 * D_ + (kc - 32) * 32 + q * 8;
                bf16x8 af = pack8(*(const float4*)hp, *(const float4*)(hp + 4));
                bf16x8 w1 = *(const bf16x8*)(sm + W1F + kc * 1024 + l * 16);
                accP1 = __builtin_amdgcn_mfma_f32_16x16x32_bf16(af, w1, accP1, 0, 0, 0);
            }
        } else {
            const unsigned* hb = hxg + sR * 8192;
            const unsigned* p0 = hb + ((4 * wv +  0 + q) * 16 + c16) * 4;
            const unsigned* p1 = hb + ((4 * wv + 32 + q) * 16 + c16) * 4;
            const unsigned* p2 = hb + ((4 * wv + 64 + q) * 16 + c16) * 4;
            const unsigned* p3 = hb + ((4 * wv + 96 + q) * 16 + c16) * 4;
            u32x4 h0v, h1v, h2v, h3v;
            ld4(p0, p1, p2, p3, h0v, h1v, h2v, h3v);
            while (bad4(h0v)) h0v = ld1(p0);
            while (bad4(h1v)) h1v = ld1(p1);
            while (bad4(h2v)) h2v = ld1(p2);
            while (bad4(h3v)) h3v = ld1(p3);
            #pragma unroll
            for (int i = 0; i < 4; ++i) {
                u32x4 hv = (i == 0) ? h0v : (i == 1) ? h1v : (i == 2) ? h2v : h3v;
                bf16x8 w1 = *(const bf16x8*)(sm + W1F + (32 + wv + 8 * i) * 1024 + l * 16);
                accP1 = __builtin_amdgcn_mfma_f32_16x16x32_bf16(fragu(hv), w1, accP1, 0, 0, 0);
            }
        }

        // ================ B: reduce + tanh + publish hidden(t) ================
        #pragma unroll
        for (int i = 0; i < 4; ++i)
            REDF[wv * REDS + (q * 4 + i) * 16 + c16] = accP1[i];
        if (c16 < 8) {
            #pragma unroll
            for (int i = 0; i < 4; ++i)
                GREDF[wv * GRS + (q * 4 + i) * 8 + c16] = accG[i];
        }
        __syncthreads();   // all waves passed A => all 128 WGs done with slot sP's readers
        float4 hsum;
        if (wv == 0) {
            // poison next slot (own blocks) — acks overlap the LDS reduce below
            unsigned* z1 = hidg + sP * 16384 + g * 128 + 2 * l;
            stcg_u(z1, POIS); stcg_u(z1 + 1, POIS);
            unsigned* z2 = hxg + sP * 8192 + g * 64 + l;
            stcg_u(z2, POIS);
            hsum = *(const float4*)(REDF + 4 * l);
            #pragma unroll
            for (int w = 1; w < 8; ++w) {
                float4 v = *(const float4*)(REDF + w * REDS + 4 * l);
                hsum.x += v.x; hsum.y += v.y; hsum.z += v.z; hsum.w += v.w;
            }
        } else if (wv == 1 || wv == 2) {
            int gt = (wv - 1) * 64 + l;
            float s = 0;
            #pragma unroll
            for (int w = 0; w < 8; ++w) s += GREDF[w * GRS + gt];
            GPF[gt] = s;
        }
        __syncthreads();   // REDF free for P2; GPF published
        if (wv == 0) {
            float t0 = tanhf(hsum.x), t1 = tanhf(hsum.y);
            float t2 = tanhf(hsum.z), t3 = tanhf(hsum.w);
            // drain poisons before publishing data (orders poison < data proof-chain)
            asm volatile("s_waitcnt vmcnt(0)" ::: "memory");
            unsigned* dst = hidg + sW * 16384 + (g * 16 + (l >> 2)) * 8 + 2 * (l & 3);
            stcg_u(dst,     packbf(t0, t1));
            stcg_u(dst + 1, packbf(t2, t3));
            // no drain, no flag — data self-validates
        }

        // ================ C: x-work for t+1 (overlaps hidden propagation) ============
        f32x4 accP1n = {0.f, 0.f, 0.f, 0.f}, accGn = {0.f, 0.f, 0.f, 0.f};
        if (t + 1 < T_) {
            const float* xt = x + (size_t)(t + 1) * (B_ * D_);
            #pragma unroll
            for (int i = 0; i < 4; ++i) {
                int kc = wv + i * 8;
                const float* xp = xt + c16 * D_ + kc * 32 + q * 8;
                bf16x8 af = pack8(*(const float4*)xp, *(const float4*)(xp + 4));
                bf16x8 w1 = *(const bf16x8*)(sm + W1F + kc * 1024 + l * 16);
                accP1n = __builtin_amdgcn_mfma_f32_16x16x32_bf16(af, w1, accP1n, 0, 0, 0);
                const char* ga = (c16 < 8) ? (sm + WGXF + kc * 512 + q * 128 + c16 * 16) : gz;
                bf16x8 wg = *(const bf16x8*)ga;
                accGn = __builtin_amdgcn_mfma_f32_16x16x32_bf16(af, wg, accGn, 0, 0, 0);
            }
        }

        // ================ D: P2 (self-validating poll loads) ================
        {
            const unsigned* hb2 = hidg + sW * 16384;
            const unsigned* q0 = hb2 + ((2 * wv +   0 + (q >> 1)) * 16 + c16) * 8 + (q & 1) * 4;
            const unsigned* q1 = hb2 + ((2 * wv +  16 + (q >> 1)) * 16 + c16) * 8 + (q & 1) * 4;
            const unsigned* q2 = hb2 + ((2 * wv +  32 + (q >> 1)) * 16 + c16) * 8 + (q & 1) * 4;
            const unsigned* q3 = hb2 + ((2 * wv +  48 + (q >> 1)) * 16 + c16) * 8 + (q & 1) * 4;
            const unsigned* q4 = hb2 + ((2 * wv +  64 + (q >> 1)) * 16 + c16) * 8 + (q & 1) * 4;
            const unsigned* q5 = hb2 + ((2 * wv +  80 + (q >> 1)) * 16 + c16) * 8 + (q & 1) * 4;
            const unsigned* q6 = hb2 + ((2 * wv +  96 + (q >> 1)) * 16 + c16) * 8 + (q & 1) * 4;
            const unsigned* q7 = hb2 + ((2 * wv + 112 + (q >> 1)) * 16 + c16) * 8 + (q & 1) * 4;
            u32x4 u0, u1, u2, u3, u4, u5, u6, u7;
            ld4(q0, q1, q2, q3, u0, u1, u2, u3);
            ld4(q4, q5, q6, q7, u4, u5, u6, u7);
            while (bad4(u0)) u0 = ld1(q0);
            while (bad4(u1)) u1 = ld1(q1);
            while (bad4(u2)) u2 = ld1(q2);
            while (bad4(u3)) u3 = ld1(q3);
            while (bad4(u4)) u4 = ld1(q4);
            while (bad4(u5)) u5 = ld1(q5);
            while (bad4(u6)) u6 = ld1(q6);
            while (bad4(u7)) u7 = ld1(q7);
            f32x4 acc2 = {0.f, 0.f, 0.f, 0.f};
            #pragma unroll
            for (int i = 0; i < 8; ++i) {
                u32x4 uv = (i == 0) ? u0 : (i == 1) ? u1 : (i == 2) ? u2 : (i == 3) ? u3
                         : (i == 4) ? u4 : (i == 5) ? u5 : (i == 6) ? u6 : u7;
                bf16x8 w2 = *(const bf16x8*)(sm + W2CF + (wv + 8 * i) * 1024 + l * 16);
                acc2 = __builtin_amdgcn_mfma_f32_16x16x32_bf16(fragu(uv), w2, acc2, 0, 0, 0);
            }
            #pragma unroll
            for (int i = 0; i < 4; ++i)
                REDF[wv * REDS + (q * 4 + i) * 16 + c16] = acc2[i];
        }

        // ================ E: finalize out, publish h(t) ================
        __syncthreads();
        float4 s4 = {0.f, 0.f, 0.f, 0.f};
        if (wv == 0) {
            #pragma unroll
            for (int w = 0; w < 8; ++w) {
                float4 v = *(const float4*)(REDF + w * REDS + 4 * l);
                s4.x += v.x; s4.y += v.y; s4.z += v.z; s4.w += v.w;
            }
        }
        __syncthreads();   // REDF free for next-step P1
        if (wv == 0) {
            float4 u4v;
            u4v.x = __shfl(s4.x, l + 2, 64); u4v.y = __shfl(s4.y, l + 2, 64);
            u4v.z = __shfl(s4.z, l + 2, 64); u4v.w = __shfl(s4.w, l + 2, 64);
            if ((l & 3) < 2) {
                int b = l >> 2, r0 = 4 * (l & 3);
                float oo[4];
                #pragma unroll
                for (int j = 0; j < 4; ++j) {
                    float hn = (j == 0) ? s4.x : (j == 1) ? s4.y : (j == 2) ? s4.z : s4.w;
                    float uj = (j == 0) ? u4v.x : (j == 1) ? u4v.y : (j == 2) ? u4v.z : u4v.w;
                    float uv = uj + GPF[b * 8 + r0 + j] + BIF[r0 + j];
                    float sig = 1.0f / (1.0f + __expf(-uv));
                    oo[j] = hn * (uv * sig);
                }
                *(float4*)(out + (size_t)t * (B_ * D_) + b * D_ + g * 8 + r0) =
                    float4{oo[0], oo[1], oo[2], oo[3]};
                unsigned* hdst = hxg + sW * 8192 + (g * 16 + b) * 4 + (r0 >> 1);
                stcg_u(hdst,     packbf(oo[0], oo[1]));
                stcg_u(hdst + 1, packbf(oo[2], oo[3]));
                // no drain, no flag — data self-validates
            }
        }

        // rotate slots: next step writes sP, reads sW, poisons sR(old)
        int tmp = sR; sR = sW; sW = sP; sP = tmp;
        accP1 = accP1n; accG = accGn;
    }
}

extern "C" void kernel_launch(void* const* d_in, const int* in_sizes, int n_in,
                              void* d_out, int out_size, void* d_ws, size_t ws_size,
                              hipStream_t stream) {
    const float* x    = (const float*)d_in[0];
    const float* h0   = (const float*)d_in[1];
    const float* W1   = (const float*)d_in[2];
    const float* W2   = (const float*)d_in[3];
    const float* Wgx  = (const float*)d_in[4];
    const float* Wgh  = (const float*)d_in[5];
    const float* bias = (const float*)d_in[6];
    float* out = (float*)d_out;

    unsigned* hidg = (unsigned*)d_ws;          // 3 slots x 64KB = 192 KB
    unsigned* hxg  = hidg + 3 * 16384;         // 3 slots x 32KB = 96 KB

    // All ring slots start as POISON (0xFF bytes); runs every launch/replay.
    hipMemsetAsync(d_ws, 0xFF, 294912, stream);

    hipFuncSetAttribute((const void*)elman8,
                        hipFuncAttributeMaxDynamicSharedMemorySize, LDS_BYTES);

    void* args[] = {(void*)&x, (void*)&h0, (void*)&W1, (void*)&W2,
                    (void*)&Wgx, (void*)&Wgh, (void*)&bias, (void*)&out,
                    (void*)&hxg, (void*)&hidg};
    hipLaunchCooperativeKernel((const void*)elman8,
                               dim3(NWG), dim3(TPB), args,
                               (unsigned)LDS_BYTES, stream);
}